// Round 2
// baseline (719.895 us; speedup 1.0000x reference)
//
#include <hip/hip_runtime.h>
#include <hip/hip_bf16.h>

#define B_N 16384
#define D_DIM 1024
#define NGRP 64
#define NCHUNK 64
#define CHUNK 256

typedef __attribute__((ext_vector_type(8))) short short8;
typedef __attribute__((ext_vector_type(8))) unsigned short ushort8;
typedef __attribute__((ext_vector_type(4))) unsigned short ushort4v;
typedef __attribute__((ext_vector_type(4))) float floatx4;

__device__ __forceinline__ float bf2f(unsigned short h) {
    union { unsigned u; float f; } c; c.u = ((unsigned)h) << 16; return c.f;
}
__device__ __forceinline__ unsigned short f2bf(float f) {
    union { float f; unsigned u; } c; c.f = f;
    unsigned r = c.u + 0x7FFFu + ((c.u >> 16) & 1u);
    return (unsigned short)(r >> 16);
}

__device__ __forceinline__ void gload_lds16(const void* g, void* l) {
    __builtin_amdgcn_global_load_lds(
        (const __attribute__((address_space(1))) unsigned int*)g,
        (__attribute__((address_space(3))) unsigned int*)l, 16, 0, 0);
}

// ---------- stable counting sort ----------
__global__ __launch_bounds__(256) void k_hist(const int* __restrict__ labels,
                                              int* __restrict__ hist) {
    __shared__ int lh[NGRP];
    int t = threadIdx.x, c = blockIdx.x;
    if (t < NGRP) lh[t] = 0;
    __syncthreads();
    int lab = labels[c * CHUNK + t];
    atomicAdd(&lh[lab], 1);
    __syncthreads();
    if (t < NGRP) hist[c * NGRP + t] = lh[t];
}

__global__ void k_scan(int* __restrict__ hist, int* __restrict__ gstart,
                       int* __restrict__ counts, float* __restrict__ scal) {
    // 64 threads, one per group
    __shared__ int cnt[NGRP];
    __shared__ int st[NGRP + 1];
    int g = threadIdx.x;
    int run = 0;
    for (int c = 0; c < NCHUNK; c++) {
        int v = hist[c * NGRP + g];
        hist[c * NGRP + g] = run;
        run += v;
    }
    cnt[g] = run;
    counts[g] = run;
    __syncthreads();
    if (g == 0) {
        int s = 0, np = 0;
        for (int i = 0; i < NGRP; i++) { st[i] = s; s += cnt[i]; np += (cnt[i] > 0); }
        st[NGRP] = s;
        scal[0] = (np > 1) ? 1.0f / (float)(np - 1) : 0.0f;
    }
    __syncthreads();
    gstart[g] = st[g];
    if (g == 0) gstart[NGRP] = st[NGRP];
    for (int c = 0; c < NCHUNK; c++) hist[c * NGRP + g] += st[g];
}

__global__ __launch_bounds__(256) void k_scatter(const int* __restrict__ labels,
                                                 const int* __restrict__ hist,
                                                 int* __restrict__ perm,
                                                 int* __restrict__ ls) {
    __shared__ int lab[CHUNK];
    int c = blockIdx.x, t = threadIdx.x;
    int i = c * CHUNK + t;
    int L = labels[i];
    lab[t] = L;
    __syncthreads();
    int rank = 0;
    for (int j = 0; j < t; j++) rank += (lab[j] == L);
    int pos = hist[c * NGRP + L] + rank;
    perm[pos] = i;
    ls[pos] = L;
}

// ---------- segment conv -> tok chunk (bf16 [2*Bc][D]) ----------
__global__ __launch_bounds__(256) void k_conv(const float* __restrict__ x,
                                              const int* __restrict__ perm,
                                              const int* __restrict__ ls,
                                              const float* __restrict__ w2, const float* __restrict__ b2,
                                              const float* __restrict__ w4, const float* __restrict__ b4,
                                              unsigned short* __restrict__ tok, int c0, int Bc) {
    const int il = blockIdx.x;        // row local to chunk
    const int i = c0 + il;            // global sorted row
    const int li = ls[i];
    const int p0 = perm[i];
    const int pm1 = (i >= 1 && ls[i - 1] == li) ? perm[i - 1] : -1;
    const int pm2 = (i >= 2 && ls[i - 2] == li) ? perm[i - 2] : -1;
    const int pp1 = (i + 1 < B_N && ls[i + 1] == li) ? perm[i + 1] : -1;
    const int c = threadIdx.x * 4;
    floatx4 z = (floatx4)0.0f;
    floatx4 x0 = *(const floatx4*)(x + (size_t)p0 * D_DIM + c);
    floatx4 xm1 = (pm1 >= 0) ? *(const floatx4*)(x + (size_t)pm1 * D_DIM + c) : z;
    floatx4 xm2 = (pm2 >= 0) ? *(const floatx4*)(x + (size_t)pm2 * D_DIM + c) : z;
    floatx4 xp1 = (pp1 >= 0) ? *(const floatx4*)(x + (size_t)pp1 * D_DIM + c) : z;
    const float w20 = w2[0], w21 = w2[1], cb2 = b2[0];
    const float w40 = w4[0], w41 = w4[1], w42 = w4[2], w43 = w4[3], cb4 = b4[0];
    ushort4v o2, o4;
#pragma unroll
    for (int j = 0; j < 4; j++) {
        float t2 = w20 * xm1[j] + w21 * x0[j] + cb2;
        float t4 = w40 * xm2[j] + w41 * xm1[j] + w42 * x0[j] + w43 * xp1[j] + cb4;
        o2[j] = f2bf(t2);
        o4[j] = f2bf(t4);
    }
    *(ushort4v*)(tok + (size_t)il * D_DIM + c) = o2;
    *(ushort4v*)(tok + (size_t)(Bc + il) * D_DIM + c) = o4;
}

// ---------- weight prep ----------
__global__ __launch_bounds__(256) void k_cast4(const float* __restrict__ src,
                                               unsigned short* __restrict__ dst, int n4) {
    int i = blockIdx.x * 256 + threadIdx.x;
    if (i < n4) {
        floatx4 v = *(const floatx4*)(src + (size_t)i * 4);
        ushort4v o;
#pragma unroll
        for (int j = 0; j < 4; j++) o[j] = f2bf(v[j]);
        *(ushort4v*)(dst + (size_t)i * 4) = o;
    }
}

__global__ __launch_bounds__(256) void k_tcast(const float* __restrict__ src,
                                               unsigned short* __restrict__ dst) {
    // dst[a][b] = bf16(src[b][a]), 1024x1024
    __shared__ float tile[32][33];
    int bx = blockIdx.x * 32, by = blockIdx.y * 32;
    int tx = threadIdx.x & 31, ty = threadIdx.x >> 5;
    for (int r = ty; r < 32; r += 8) tile[r][tx] = src[(size_t)(by + r) * D_DIM + bx + tx];
    __syncthreads();
    for (int r = ty; r < 32; r += 8) dst[(size_t)(bx + r) * D_DIM + by + tx] = f2bf(tile[tx][r]);
}

__global__ __launch_bounds__(256) void k_biasc(const float* __restrict__ lin_w,
                                               const float* __restrict__ lin_b,
                                               const float* __restrict__ ob,
                                               float* __restrict__ biasc) {
    int n = blockIdx.x * 256 + threadIdx.x;
    float s = lin_b[n];
    const float* wr = lin_w + (size_t)n * D_DIM;
    for (int t = 0; t < D_DIM; t++) s += ob[t] * wr[t];
    biasc[n] = s;
}

// ---------- inter path (fp32, tiny) ----------
__global__ __launch_bounds__(256) void k_u(const float* __restrict__ x,
                                           const int* __restrict__ perm,
                                           const int* __restrict__ gstart,
                                           const int* __restrict__ counts,
                                           const float* __restrict__ Wfull,
                                           const float* __restrict__ bfull,
                                           float* __restrict__ u) {
    const int g = blockIdx.y;
    const int n = blockIdx.x * 256 + threadIdx.x;
    __shared__ __align__(16) float xr[D_DIM];
    const int cnt = counts[g];
    const int row = (cnt > 0) ? perm[gstart[g]] : 0;
    for (int k = threadIdx.x; k < D_DIM; k += 256) xr[k] = x[(size_t)row * D_DIM + k];
    __syncthreads();
    const floatx4* wr4 = (const floatx4*)(Wfull + (size_t)(2 * D_DIM + n) * D_DIM);
    const floatx4* xr4 = (const floatx4*)xr;
    float s = bfull[2 * D_DIM + n];
    for (int k4 = 0; k4 < D_DIM / 4; k4++) {
        floatx4 a = xr4[k4], b = wr4[k4];
        s += a[0] * b[0] + a[1] * b[1] + a[2] * b[2] + a[3] * b[3];
    }
    u[g * D_DIM + n] = s;
}

__global__ __launch_bounds__(256) void k_f(const float* __restrict__ u,
                                           const int* __restrict__ counts,
                                           const float* __restrict__ W,
                                           const float* __restrict__ b,
                                           float* __restrict__ f) {
    const int g = blockIdx.y;
    const int n = blockIdx.x * 256 + threadIdx.x;
    __shared__ __align__(16) float ur[D_DIM];
    const int cnt = counts[g];
    for (int k = threadIdx.x; k < D_DIM; k += 256) ur[k] = u[g * D_DIM + k];
    __syncthreads();
    const floatx4* wr4 = (const floatx4*)(W + (size_t)n * D_DIM);
    const floatx4* ur4 = (const floatx4*)ur;
    float s = b[n];
    for (int k4 = 0; k4 < D_DIM / 4; k4++) {
        floatx4 a = ur4[k4], w = wr4[k4];
        s += a[0] * w[0] + a[1] * w[1] + a[2] * w[2] + a[3] * w[3];
    }
    f[g * D_DIM + n] = (cnt > 0) ? s : 0.0f;
}

__global__ __launch_bounds__(256) void k_imean(const float* __restrict__ f,
                                               const float* __restrict__ scal,
                                               float* __restrict__ im) {
    int c = blockIdx.x * 256 + threadIdx.x;
    float s = 0.0f;
    for (int g = 0; g < NGRP; g++) s += f[g * D_DIM + c];
    float fl = scal[0];
    for (int g = 0; g < NGRP; g++) im[g * D_DIM + c] = (s - f[g * D_DIM + c]) * fl;
}

// ---------- bf16 MFMA GEMM: C[m][n] = sum_k A[m][k]*W[n][k] (+epilogue) ----------
// MODE 0: outb = bf16(acc + bias[n])          (qkv projection)
// MODE 1: outb = bf16(acc)                    (Wc = lin_w @ intra_out_w)
// MODE 2: outf[perm[m]][n] = acc + bias[n] + imean[ls[m]][n]   (final, scattered)
template <int MODE>
__global__ __launch_bounds__(256)
void gemm_bt(const unsigned short* __restrict__ A,
             const unsigned short* __restrict__ W,
             int M, int N, int K,
             const float* __restrict__ bias,
             unsigned short* __restrict__ outb,
             float* __restrict__ outf,
             const int* __restrict__ perm,
             const int* __restrict__ ls,
             const float* __restrict__ imean) {
    __shared__ __align__(16) unsigned short sA[128 * 64];
    __shared__ __align__(16) unsigned short sB[128 * 64];
    const int t = threadIdx.x;
    const int lane = t & 63, wv = t >> 6;
    const int m0 = blockIdx.y * 128, n0 = blockIdx.x * 128;
    const int wm = (wv & 1) * 64, wn = (wv >> 1) * 64;
    const int l15 = lane & 15, quad = lane >> 4;

    floatx4 acc[4][4];
#pragma unroll
    for (int i = 0; i < 4; i++)
#pragma unroll
        for (int j = 0; j < 4; j++) acc[i][j] = (floatx4)0.0f;

    for (int k0 = 0; k0 < K; k0 += 64) {
#pragma unroll
        for (int r = 0; r < 4; r++) {
            const int chunk = r * 256 + wv * 64;   // wave-uniform LDS chunk base
            const int idx = chunk + lane;          // per-lane 16B chunk
            const int row = idx >> 3, kb = idx & 7;
            gload_lds16(A + (size_t)(m0 + row) * K + k0 + kb * 8, &sA[chunk * 8]);
            gload_lds16(W + (size_t)(n0 + row) * K + k0 + kb * 8, &sB[chunk * 8]);
        }
        __syncthreads();
#pragma unroll
        for (int kk = 0; kk < 64; kk += 32) {
            short8 av[4], bv[4];
#pragma unroll
            for (int mt = 0; mt < 4; mt++)
                av[mt] = *(const short8*)&sA[(wm + mt * 16 + l15) * 64 + kk + quad * 8];
#pragma unroll
            for (int nt = 0; nt < 4; nt++)
                bv[nt] = *(const short8*)&sB[(wn + nt * 16 + l15) * 64 + kk + quad * 8];
#pragma unroll
            for (int mt = 0; mt < 4; mt++)
#pragma unroll
                for (int nt = 0; nt < 4; nt++)
                    acc[mt][nt] = __builtin_amdgcn_mfma_f32_16x16x32_bf16(
                        av[mt], bv[nt], acc[mt][nt], 0, 0, 0);
        }
        __syncthreads();
    }

    if (MODE == 0 || MODE == 1) {
#pragma unroll
        for (int nt = 0; nt < 4; nt++) {
            const int gc = n0 + wn + nt * 16 + l15;
            const float bb = (MODE == 0) ? bias[gc] : 0.0f;
#pragma unroll
            for (int mt = 0; mt < 4; mt++) {
                const int gr = m0 + wm + mt * 16 + quad * 4;
#pragma unroll
                for (int r = 0; r < 4; r++)
                    outb[(size_t)(gr + r) * N + gc] = f2bf(acc[mt][nt][r] + bb);
            }
        }
    } else {
        float bb[4];
        int gc4[4];
#pragma unroll
        for (int nt = 0; nt < 4; nt++) {
            gc4[nt] = n0 + wn + nt * 16 + l15;
            bb[nt] = bias[gc4[nt]];
        }
#pragma unroll
        for (int mt = 0; mt < 4; mt++) {
#pragma unroll
            for (int r = 0; r < 4; r++) {
                const int i = m0 + wm + mt * 16 + quad * 4 + r;
                const int orow = perm[i];
                const int lg = ls[i];
#pragma unroll
                for (int nt = 0; nt < 4; nt++)
                    outf[(size_t)orow * N + gc4[nt]] =
                        acc[mt][nt][r] + bb[nt] + imean[lg * D_DIM + gc4[nt]];
            }
        }
    }
}

// ---------- S=2 attention combine on a qkv chunk -> om (bf16) ----------
__global__ __launch_bounds__(256) void k_attn(const unsigned short* __restrict__ qkv,
                                              unsigned short* __restrict__ om,
                                              int c0, int Bc) {
    const int t = threadIdx.x;
    const int lane = t & 63, wv = t >> 6;
    const int bl = blockIdx.x * 4 + wv;          // chunk-local position
    const size_t r0 = (size_t)bl * 3072;
    const size_t r1 = (size_t)(Bc + bl) * 3072;
    float c0w[2], c1w[2];
#pragma unroll
    for (int h = 0; h < 2; h++) {
        const int off = h * 512 + lane * 8;
        short8 q0 = *(const short8*)(qkv + r0 + off);
        short8 q1 = *(const short8*)(qkv + r1 + off);
        short8 k0 = *(const short8*)(qkv + r0 + 1024 + off);
        short8 k1 = *(const short8*)(qkv + r1 + 1024 + off);
        float s00 = 0, s01 = 0, s10 = 0, s11 = 0;
#pragma unroll
        for (int j = 0; j < 8; j++) {
            float q0f = bf2f((unsigned short)q0[j]), q1f = bf2f((unsigned short)q1[j]);
            float k0f = bf2f((unsigned short)k0[j]), k1f = bf2f((unsigned short)k1[j]);
            s00 += q0f * k0f; s01 += q0f * k1f; s10 += q1f * k0f; s11 += q1f * k1f;
        }
#pragma unroll
        for (int d = 32; d > 0; d >>= 1) {
            s00 += __shfl_xor(s00, d, 64);
            s01 += __shfl_xor(s01, d, 64);
            s10 += __shfl_xor(s10, d, 64);
            s11 += __shfl_xor(s11, d, 64);
        }
        const float sc = 0.044194173824159216f;  // 1/sqrt(512)
        s00 *= sc; s01 *= sc; s10 *= sc; s11 *= sc;
        float m0 = fmaxf(s00, s01), e00 = __expf(s00 - m0), e01 = __expf(s01 - m0);
        float w01 = e01 / (e00 + e01), w00 = 1.0f - w01;
        float m1 = fmaxf(s10, s11), e10 = __expf(s10 - m1), e11 = __expf(s11 - m1);
        float w11 = e11 / (e10 + e11), w10 = 1.0f - w11;
        c0w[h] = 0.5f * (w00 + w10);
        c1w[h] = 0.5f * (w01 + w11);
    }
#pragma unroll
    for (int h = 0; h < 2; h++) {
        const int off = h * 512 + lane * 8;
        short8 v0 = *(const short8*)(qkv + r0 + 2048 + off);
        short8 v1 = *(const short8*)(qkv + r1 + 2048 + off);
        ushort8 o;
#pragma unroll
        for (int j = 0; j < 8; j++) {
            float val = c0w[h] * bf2f((unsigned short)v0[j]) + c1w[h] * bf2f((unsigned short)v1[j]);
            o[j] = f2bf(val);
        }
        *(ushort8*)(om + (size_t)(c0 + bl) * D_DIM + off) = o;
    }
}

extern "C" void kernel_launch(void* const* d_in, const int* in_sizes, int n_in,
                              void* d_out, int out_size, void* d_ws, size_t ws_size,
                              hipStream_t stream) {
    const float* x = (const float*)d_in[0];
    const int* labels = (const int*)d_in[1];
    const float* conv_w2 = (const float*)d_in[3];
    const float* conv_b2 = (const float*)d_in[4];
    const float* conv_w4 = (const float*)d_in[5];
    const float* conv_b4 = (const float*)d_in[6];
    const float* intra_in_w = (const float*)d_in[7];
    const float* intra_in_b = (const float*)d_in[8];
    const float* intra_out_w = (const float*)d_in[9];
    const float* intra_out_b = (const float*)d_in[10];
    const float* inter_in_w = (const float*)d_in[11];
    const float* inter_in_b = (const float*)d_in[12];
    const float* inter_out_w = (const float*)d_in[13];
    const float* inter_out_b = (const float*)d_in[14];
    const float* lin_w = (const float*)d_in[15];
    const float* lin_b = (const float*)d_in[16];
    float* out = (float*)d_out;

    char* p = (char*)d_ws;
    auto alloc = [&](size_t bytes) -> void* {
        void* r = (void*)p;
        p += (bytes + 255) & ~(size_t)255;
        return r;
    };
    // ---- fixed buffers (~45 MB) ----
    int* perm = (int*)alloc(B_N * 4);
    int* lss = (int*)alloc(B_N * 4);
    int* hist = (int*)alloc(NCHUNK * NGRP * 4);
    int* gstart = (int*)alloc((NGRP + 1) * 4);
    int* counts = (int*)alloc(NGRP * 4);
    float* scal = (float*)alloc(4);
    unsigned short* om = (unsigned short*)alloc((size_t)B_N * D_DIM * 2);       // 32 MB
    unsigned short* W1b = (unsigned short*)alloc((size_t)3 * D_DIM * D_DIM * 2); // 6 MB
    unsigned short* linwb = (unsigned short*)alloc((size_t)D_DIM * D_DIM * 2);
    unsigned short* WoT = (unsigned short*)alloc((size_t)D_DIM * D_DIM * 2);
    unsigned short* Wc = (unsigned short*)alloc((size_t)D_DIM * D_DIM * 2);
    float* u = (float*)alloc((size_t)NGRP * D_DIM * 4);
    float* fbuf = (float*)alloc((size_t)NGRP * D_DIM * 4);
    float* imean = (float*)alloc((size_t)NGRP * D_DIM * 4);
    float* biasc = (float*)alloc(D_DIM * 4);

    // ---- adaptive chunk size: tok_chunk + qkv_chunk = 16384*Bc bytes ----
    size_t used = (size_t)(p - (char*)d_ws);
    size_t remain = (ws_size > used) ? (ws_size - used) : 0;
    int Bc = 512;
    const int cand[6] = {16384, 8192, 4096, 2048, 1024, 512};
    for (int ci = 0; ci < 6; ci++) {
        if ((size_t)16384 * cand[ci] + 8192 <= remain) { Bc = cand[ci]; break; }
    }
    unsigned short* tokc = (unsigned short*)alloc((size_t)2 * Bc * D_DIM * 2);
    unsigned short* qkvc = (unsigned short*)alloc((size_t)2 * Bc * 3 * D_DIM * 2);

    // ---- sort ----
    k_hist<<<NCHUNK, CHUNK, 0, stream>>>(labels, hist);
    k_scan<<<1, NGRP, 0, stream>>>(hist, gstart, counts, scal);
    k_scatter<<<NCHUNK, CHUNK, 0, stream>>>(labels, hist, perm, lss);
    // ---- weight prep ----
    k_cast4<<<(3 * D_DIM * D_DIM / 4 + 255) / 256, 256, 0, stream>>>(intra_in_w, W1b,
                                                                     3 * D_DIM * D_DIM / 4);
    k_cast4<<<(D_DIM * D_DIM / 4 + 255) / 256, 256, 0, stream>>>(lin_w, linwb,
                                                                 D_DIM * D_DIM / 4);
    k_tcast<<<dim3(32, 32), 256, 0, stream>>>(intra_out_w, WoT);
    gemm_bt<1><<<dim3(8, 8), 256, 0, stream>>>(linwb, WoT, 1024, 1024, 1024, nullptr, Wc,
                                               nullptr, nullptr, nullptr, nullptr);
    k_biasc<<<4, 256, 0, stream>>>(lin_w, lin_b, intra_out_b, biasc);
    // ---- inter path (fp32) ----
    k_u<<<dim3(4, NGRP), 256, 0, stream>>>(x, perm, gstart, counts, inter_in_w, inter_in_b, u);
    k_f<<<dim3(4, NGRP), 256, 0, stream>>>(u, counts, inter_out_w, inter_out_b, fbuf);
    k_imean<<<4, 256, 0, stream>>>(fbuf, scal, imean);
    // ---- chunked conv -> qkv -> attention combine ----
    const int nchunks = B_N / Bc;
    for (int c = 0; c < nchunks; c++) {
        const int c0 = c * Bc;
        k_conv<<<Bc, 256, 0, stream>>>(x, perm, lss, conv_w2, conv_b2, conv_w4, conv_b4,
                                       tokc, c0, Bc);
        gemm_bt<0><<<dim3(24, 2 * Bc / 128), 256, 0, stream>>>(
            tokc, W1b, 2 * Bc, 3 * D_DIM, D_DIM, intra_in_b, qkvc, nullptr, nullptr,
            nullptr, nullptr);
        k_attn<<<Bc / 4, 256, 0, stream>>>(qkvc, om, c0, Bc);
    }
    // ---- final folded GEMM + scatter ----
    gemm_bt<2><<<dim3(8, 128), 256, 0, stream>>>(om, Wc, B_N, D_DIM, D_DIM, biasc, nullptr,
                                                 out, perm, lss, imean);
}

// Round 3
// 668.085 us; speedup vs baseline: 1.0776x; 1.0776x over previous
//
#include <hip/hip_runtime.h>
#include <hip/hip_bf16.h>

#define B_N 16384
#define D_DIM 1024
#define NGRP 64
#define NCHUNK 64
#define CHUNK 256

typedef __attribute__((ext_vector_type(8))) short short8;
typedef __attribute__((ext_vector_type(8))) unsigned short ushort8;
typedef __attribute__((ext_vector_type(4))) unsigned short ushort4v;
typedef __attribute__((ext_vector_type(4))) float floatx4;

__device__ __forceinline__ float bf2f(unsigned short h) {
    union { unsigned u; float f; } c; c.u = ((unsigned)h) << 16; return c.f;
}
__device__ __forceinline__ unsigned short f2bf(float f) {
    union { float f; unsigned u; } c; c.f = f;
    unsigned r = c.u + 0x7FFFu + ((c.u >> 16) & 1u);
    return (unsigned short)(r >> 16);
}

__device__ __forceinline__ void gload_lds16(const void* g, void* l) {
    __builtin_amdgcn_global_load_lds(
        (const __attribute__((address_space(1))) unsigned int*)g,
        (__attribute__((address_space(3))) unsigned int*)l, 16, 0, 0);
}

// ---------- stable counting sort ----------
__global__ __launch_bounds__(256) void k_hist(const int* __restrict__ labels,
                                              int* __restrict__ hist) {
    __shared__ int lh[NGRP];
    int t = threadIdx.x, c = blockIdx.x;
    if (t < NGRP) lh[t] = 0;
    __syncthreads();
    int lab = labels[c * CHUNK + t];
    atomicAdd(&lh[lab], 1);
    __syncthreads();
    if (t < NGRP) hist[c * NGRP + t] = lh[t];
}

__global__ void k_scan(int* __restrict__ hist, int* __restrict__ gstart,
                       int* __restrict__ counts, float* __restrict__ scal) {
    // 64 threads, one per group
    __shared__ int cnt[NGRP];
    __shared__ int st[NGRP + 1];
    int g = threadIdx.x;
    int run = 0;
    for (int c = 0; c < NCHUNK; c++) {
        int v = hist[c * NGRP + g];
        hist[c * NGRP + g] = run;
        run += v;
    }
    cnt[g] = run;
    counts[g] = run;
    __syncthreads();
    if (g == 0) {
        int s = 0, np = 0;
        for (int i = 0; i < NGRP; i++) { st[i] = s; s += cnt[i]; np += (cnt[i] > 0); }
        st[NGRP] = s;
        scal[0] = (np > 1) ? 1.0f / (float)(np - 1) : 0.0f;
    }
    __syncthreads();
    gstart[g] = st[g];
    if (g == 0) gstart[NGRP] = st[NGRP];
    for (int c = 0; c < NCHUNK; c++) hist[c * NGRP + g] += st[g];
}

__global__ __launch_bounds__(256) void k_scatter(const int* __restrict__ labels,
                                                 const int* __restrict__ hist,
                                                 int* __restrict__ perm,
                                                 int* __restrict__ ls) {
    __shared__ int lab[CHUNK];
    int c = blockIdx.x, t = threadIdx.x;
    int i = c * CHUNK + t;
    int L = labels[i];
    lab[t] = L;
    __syncthreads();
    int rank = 0;
    for (int j = 0; j < t; j++) rank += (lab[j] == L);
    int pos = hist[c * NGRP + L] + rank;
    perm[pos] = i;
    ls[pos] = L;
}

// ---------- segment conv -> tok chunk (bf16 [2*Bc][D]) ----------
__global__ __launch_bounds__(256) void k_conv(const float* __restrict__ x,
                                              const int* __restrict__ perm,
                                              const int* __restrict__ ls,
                                              const float* __restrict__ w2, const float* __restrict__ b2,
                                              const float* __restrict__ w4, const float* __restrict__ b4,
                                              unsigned short* __restrict__ tok, int c0, int Bc) {
    const int il = blockIdx.x;        // row local to chunk
    const int i = c0 + il;            // global sorted row
    const int li = ls[i];
    const int p0 = perm[i];
    const int pm1 = (i >= 1 && ls[i - 1] == li) ? perm[i - 1] : -1;
    const int pm2 = (i >= 2 && ls[i - 2] == li) ? perm[i - 2] : -1;
    const int pp1 = (i + 1 < B_N && ls[i + 1] == li) ? perm[i + 1] : -1;
    const int c = threadIdx.x * 4;
    floatx4 z = (floatx4)0.0f;
    floatx4 x0 = *(const floatx4*)(x + (size_t)p0 * D_DIM + c);
    floatx4 xm1 = (pm1 >= 0) ? *(const floatx4*)(x + (size_t)pm1 * D_DIM + c) : z;
    floatx4 xm2 = (pm2 >= 0) ? *(const floatx4*)(x + (size_t)pm2 * D_DIM + c) : z;
    floatx4 xp1 = (pp1 >= 0) ? *(const floatx4*)(x + (size_t)pp1 * D_DIM + c) : z;
    const float w20 = w2[0], w21 = w2[1], cb2 = b2[0];
    const float w40 = w4[0], w41 = w4[1], w42 = w4[2], w43 = w4[3], cb4 = b4[0];
    ushort4v o2, o4;
#pragma unroll
    for (int j = 0; j < 4; j++) {
        float t2 = w20 * xm1[j] + w21 * x0[j] + cb2;
        float t4 = w40 * xm2[j] + w41 * xm1[j] + w42 * x0[j] + w43 * xp1[j] + cb4;
        o2[j] = f2bf(t2);
        o4[j] = f2bf(t4);
    }
    *(ushort4v*)(tok + (size_t)il * D_DIM + c) = o2;
    *(ushort4v*)(tok + (size_t)(Bc + il) * D_DIM + c) = o4;
}

// ---------- weight prep ----------
__global__ __launch_bounds__(256) void k_cast4(const float* __restrict__ src,
                                               unsigned short* __restrict__ dst, int n4) {
    int i = blockIdx.x * 256 + threadIdx.x;
    if (i < n4) {
        floatx4 v = *(const floatx4*)(src + (size_t)i * 4);
        ushort4v o;
#pragma unroll
        for (int j = 0; j < 4; j++) o[j] = f2bf(v[j]);
        *(ushort4v*)(dst + (size_t)i * 4) = o;
    }
}

__global__ __launch_bounds__(256) void k_tcast(const float* __restrict__ src,
                                               unsigned short* __restrict__ dst) {
    // dst[a][b] = bf16(src[b][a]), 1024x1024
    __shared__ float tile[32][33];
    int bx = blockIdx.x * 32, by = blockIdx.y * 32;
    int tx = threadIdx.x & 31, ty = threadIdx.x >> 5;
    for (int r = ty; r < 32; r += 8) tile[r][tx] = src[(size_t)(by + r) * D_DIM + bx + tx];
    __syncthreads();
    for (int r = ty; r < 32; r += 8) dst[(size_t)(bx + r) * D_DIM + by + tx] = f2bf(tile[tx][r]);
}

__global__ __launch_bounds__(256) void k_biasc(const float* __restrict__ lin_w,
                                               const float* __restrict__ lin_b,
                                               const float* __restrict__ ob,
                                               float* __restrict__ biasc) {
    int n = blockIdx.x * 256 + threadIdx.x;
    float s = lin_b[n];
    const float* wr = lin_w + (size_t)n * D_DIM;
    for (int t = 0; t < D_DIM; t++) s += ob[t] * wr[t];
    biasc[n] = s;
}

// ---------- inter path (fp32, tiny) ----------
__global__ __launch_bounds__(256) void k_u(const float* __restrict__ x,
                                           const int* __restrict__ perm,
                                           const int* __restrict__ gstart,
                                           const int* __restrict__ counts,
                                           const float* __restrict__ Wfull,
                                           const float* __restrict__ bfull,
                                           float* __restrict__ u) {
    const int g = blockIdx.y;
    const int n = blockIdx.x * 256 + threadIdx.x;
    __shared__ __align__(16) float xr[D_DIM];
    const int cnt = counts[g];
    const int row = (cnt > 0) ? perm[gstart[g]] : 0;
    for (int k = threadIdx.x; k < D_DIM; k += 256) xr[k] = x[(size_t)row * D_DIM + k];
    __syncthreads();
    const floatx4* wr4 = (const floatx4*)(Wfull + (size_t)(2 * D_DIM + n) * D_DIM);
    const floatx4* xr4 = (const floatx4*)xr;
    float s = bfull[2 * D_DIM + n];
    for (int k4 = 0; k4 < D_DIM / 4; k4++) {
        floatx4 a = xr4[k4], b = wr4[k4];
        s += a[0] * b[0] + a[1] * b[1] + a[2] * b[2] + a[3] * b[3];
    }
    u[g * D_DIM + n] = s;
}

__global__ __launch_bounds__(256) void k_f(const float* __restrict__ u,
                                           const int* __restrict__ counts,
                                           const float* __restrict__ W,
                                           const float* __restrict__ b,
                                           float* __restrict__ f) {
    const int g = blockIdx.y;
    const int n = blockIdx.x * 256 + threadIdx.x;
    __shared__ __align__(16) float ur[D_DIM];
    const int cnt = counts[g];
    for (int k = threadIdx.x; k < D_DIM; k += 256) ur[k] = u[g * D_DIM + k];
    __syncthreads();
    const floatx4* wr4 = (const floatx4*)(W + (size_t)n * D_DIM);
    const floatx4* ur4 = (const floatx4*)ur;
    float s = b[n];
    for (int k4 = 0; k4 < D_DIM / 4; k4++) {
        floatx4 a = ur4[k4], w = wr4[k4];
        s += a[0] * w[0] + a[1] * w[1] + a[2] * w[2] + a[3] * w[3];
    }
    f[g * D_DIM + n] = (cnt > 0) ? s : 0.0f;
}

__global__ __launch_bounds__(256) void k_imean(const float* __restrict__ f,
                                               const float* __restrict__ scal,
                                               float* __restrict__ im) {
    int c = blockIdx.x * 256 + threadIdx.x;
    float s = 0.0f;
    for (int g = 0; g < NGRP; g++) s += f[g * D_DIM + c];
    float fl = scal[0];
    for (int g = 0; g < NGRP; g++) im[g * D_DIM + c] = (s - f[g * D_DIM + c]) * fl;
}

// ---------- bf16 MFMA GEMM: C[m][n] = sum_k A[m][k]*W[n][k] (+epilogue) ----------
// LDS layout is XOR-swizzled at 16B-chunk granularity to kill bank conflicts:
//   LDS[row][c] holds global chunk (c ^ (row&7)) of that row.
//   (row stride = 128B = 32 banks, so unswizzled reads were 16-way conflicted)
// MODE 0: outb = bf16(acc + bias[n])          (qkv projection)
// MODE 1: outb = bf16(acc)                    (Wc = lin_w @ intra_out_w)
// MODE 2: outf[perm[m]][n] = acc + bias[n] + imean[ls[m]][n]   (final, scattered)
template <int MODE>
__global__ __launch_bounds__(256)
void gemm_bt(const unsigned short* __restrict__ A,
             const unsigned short* __restrict__ W,
             int M, int N, int K,
             const float* __restrict__ bias,
             unsigned short* __restrict__ outb,
             float* __restrict__ outf,
             const int* __restrict__ perm,
             const int* __restrict__ ls,
             const float* __restrict__ imean) {
    __shared__ __align__(16) unsigned short sA[128 * 64];
    __shared__ __align__(16) unsigned short sB[128 * 64];
    const int t = threadIdx.x;
    const int lane = t & 63, wv = t >> 6;
    const int m0 = blockIdx.y * 128, n0 = blockIdx.x * 128;
    const int wm = (wv & 1) * 64, wn = (wv >> 1) * 64;
    const int l15 = lane & 15, quad = lane >> 4;
    const int sw = l15 & 7;  // read-side swizzle key (== row&7 for all fragment rows)

    floatx4 acc[4][4];
#pragma unroll
    for (int i = 0; i < 4; i++)
#pragma unroll
        for (int j = 0; j < 4; j++) acc[i][j] = (floatx4)0.0f;

    for (int k0 = 0; k0 < K; k0 += 64) {
#pragma unroll
        for (int r = 0; r < 4; r++) {
            const int chunk = r * 256 + wv * 64;   // wave-uniform LDS chunk base
            const int idx = chunk + lane;          // per-lane 16B LDS slot
            const int row = idx >> 3;
            const int kb = (idx & 7) ^ (row & 7);  // swizzled global k-chunk
            gload_lds16(A + (size_t)(m0 + row) * K + k0 + kb * 8, &sA[chunk * 8]);
            gload_lds16(W + (size_t)(n0 + row) * K + k0 + kb * 8, &sB[chunk * 8]);
        }
        __syncthreads();
#pragma unroll
        for (int kk = 0; kk < 64; kk += 32) {
            const int kc = kk >> 3;  // base k-chunk index (0 or 4)
            short8 av[4], bv[4];
#pragma unroll
            for (int mt = 0; mt < 4; mt++)
                av[mt] = *(const short8*)&sA[(wm + mt * 16 + l15) * 64 +
                                             (((kc + quad) ^ sw) << 3)];
#pragma unroll
            for (int nt = 0; nt < 4; nt++)
                bv[nt] = *(const short8*)&sB[(wn + nt * 16 + l15) * 64 +
                                             (((kc + quad) ^ sw) << 3)];
#pragma unroll
            for (int mt = 0; mt < 4; mt++)
#pragma unroll
                for (int nt = 0; nt < 4; nt++)
                    acc[mt][nt] = __builtin_amdgcn_mfma_f32_16x16x32_bf16(
                        av[mt], bv[nt], acc[mt][nt], 0, 0, 0);
        }
        __syncthreads();
    }

    if (MODE == 0 || MODE == 1) {
#pragma unroll
        for (int nt = 0; nt < 4; nt++) {
            const int gc = n0 + wn + nt * 16 + l15;
            const float bb = (MODE == 0) ? bias[gc] : 0.0f;
#pragma unroll
            for (int mt = 0; mt < 4; mt++) {
                const int gr = m0 + wm + mt * 16 + quad * 4;
#pragma unroll
                for (int r = 0; r < 4; r++)
                    outb[(size_t)(gr + r) * N + gc] = f2bf(acc[mt][nt][r] + bb);
            }
        }
    } else {
        float bb[4];
        int gc4[4];
#pragma unroll
        for (int nt = 0; nt < 4; nt++) {
            gc4[nt] = n0 + wn + nt * 16 + l15;
            bb[nt] = bias[gc4[nt]];
        }
#pragma unroll
        for (int mt = 0; mt < 4; mt++) {
#pragma unroll
            for (int r = 0; r < 4; r++) {
                const int i = m0 + wm + mt * 16 + quad * 4 + r;
                const int orow = perm[i];
                const int lg = ls[i];
#pragma unroll
                for (int nt = 0; nt < 4; nt++)
                    outf[(size_t)orow * N + gc4[nt]] =
                        acc[mt][nt][r] + bb[nt] + imean[lg * D_DIM + gc4[nt]];
            }
        }
    }
}

// ---------- S=2 attention combine on a qkv chunk -> om (bf16) ----------
__global__ __launch_bounds__(256) void k_attn(const unsigned short* __restrict__ qkv,
                                              unsigned short* __restrict__ om,
                                              int c0, int Bc) {
    const int t = threadIdx.x;
    const int lane = t & 63, wv = t >> 6;
    const int bl = blockIdx.x * 4 + wv;          // chunk-local position
    const size_t r0 = (size_t)bl * 3072;
    const size_t r1 = (size_t)(Bc + bl) * 3072;
    float c0w[2], c1w[2];
#pragma unroll
    for (int h = 0; h < 2; h++) {
        const int off = h * 512 + lane * 8;
        short8 q0 = *(const short8*)(qkv + r0 + off);
        short8 q1 = *(const short8*)(qkv + r1 + off);
        short8 k0 = *(const short8*)(qkv + r0 + 1024 + off);
        short8 k1 = *(const short8*)(qkv + r1 + 1024 + off);
        float s00 = 0, s01 = 0, s10 = 0, s11 = 0;
#pragma unroll
        for (int j = 0; j < 8; j++) {
            float q0f = bf2f((unsigned short)q0[j]), q1f = bf2f((unsigned short)q1[j]);
            float k0f = bf2f((unsigned short)k0[j]), k1f = bf2f((unsigned short)k1[j]);
            s00 += q0f * k0f; s01 += q0f * k1f; s10 += q1f * k0f; s11 += q1f * k1f;
        }
#pragma unroll
        for (int d = 32; d > 0; d >>= 1) {
            s00 += __shfl_xor(s00, d, 64);
            s01 += __shfl_xor(s01, d, 64);
            s10 += __shfl_xor(s10, d, 64);
            s11 += __shfl_xor(s11, d, 64);
        }
        const float sc = 0.044194173824159216f;  // 1/sqrt(512)
        s00 *= sc; s01 *= sc; s10 *= sc; s11 *= sc;
        float m0 = fmaxf(s00, s01), e00 = __expf(s00 - m0), e01 = __expf(s01 - m0);
        float w01 = e01 / (e00 + e01), w00 = 1.0f - w01;
        float m1 = fmaxf(s10, s11), e10 = __expf(s10 - m1), e11 = __expf(s11 - m1);
        float w11 = e11 / (e10 + e11), w10 = 1.0f - w11;
        c0w[h] = 0.5f * (w00 + w10);
        c1w[h] = 0.5f * (w01 + w11);
    }
#pragma unroll
    for (int h = 0; h < 2; h++) {
        const int off = h * 512 + lane * 8;
        short8 v0 = *(const short8*)(qkv + r0 + 2048 + off);
        short8 v1 = *(const short8*)(qkv + r1 + 2048 + off);
        ushort8 o;
#pragma unroll
        for (int j = 0; j < 8; j++) {
            float val = c0w[h] * bf2f((unsigned short)v0[j]) + c1w[h] * bf2f((unsigned short)v1[j]);
            o[j] = f2bf(val);
        }
        *(ushort8*)(om + (size_t)(c0 + bl) * D_DIM + off) = o;
    }
}

extern "C" void kernel_launch(void* const* d_in, const int* in_sizes, int n_in,
                              void* d_out, int out_size, void* d_ws, size_t ws_size,
                              hipStream_t stream) {
    const float* x = (const float*)d_in[0];
    const int* labels = (const int*)d_in[1];
    const float* conv_w2 = (const float*)d_in[3];
    const float* conv_b2 = (const float*)d_in[4];
    const float* conv_w4 = (const float*)d_in[5];
    const float* conv_b4 = (const float*)d_in[6];
    const float* intra_in_w = (const float*)d_in[7];
    const float* intra_in_b = (const float*)d_in[8];
    const float* intra_out_w = (const float*)d_in[9];
    const float* intra_out_b = (const float*)d_in[10];
    const float* inter_in_w = (const float*)d_in[11];
    const float* inter_in_b = (const float*)d_in[12];
    const float* inter_out_w = (const float*)d_in[13];
    const float* inter_out_b = (const float*)d_in[14];
    const float* lin_w = (const float*)d_in[15];
    const float* lin_b = (const float*)d_in[16];
    float* out = (float*)d_out;

    char* p = (char*)d_ws;
    auto alloc = [&](size_t bytes) -> void* {
        void* r = (void*)p;
        p += (bytes + 255) & ~(size_t)255;
        return r;
    };
    // ---- fixed buffers (~45 MB) ----
    int* perm = (int*)alloc(B_N * 4);
    int* lss = (int*)alloc(B_N * 4);
    int* hist = (int*)alloc(NCHUNK * NGRP * 4);
    int* gstart = (int*)alloc((NGRP + 1) * 4);
    int* counts = (int*)alloc(NGRP * 4);
    float* scal = (float*)alloc(4);
    unsigned short* om = (unsigned short*)alloc((size_t)B_N * D_DIM * 2);       // 32 MB
    unsigned short* W1b = (unsigned short*)alloc((size_t)3 * D_DIM * D_DIM * 2); // 6 MB
    unsigned short* linwb = (unsigned short*)alloc((size_t)D_DIM * D_DIM * 2);
    unsigned short* WoT = (unsigned short*)alloc((size_t)D_DIM * D_DIM * 2);
    unsigned short* Wc = (unsigned short*)alloc((size_t)D_DIM * D_DIM * 2);
    float* u = (float*)alloc((size_t)NGRP * D_DIM * 4);
    float* fbuf = (float*)alloc((size_t)NGRP * D_DIM * 4);
    float* imean = (float*)alloc((size_t)NGRP * D_DIM * 4);
    float* biasc = (float*)alloc(D_DIM * 4);

    // ---- adaptive chunk size: tok_chunk + qkv_chunk = 16384*Bc bytes ----
    size_t used = (size_t)(p - (char*)d_ws);
    size_t remain = (ws_size > used) ? (ws_size - used) : 0;
    int Bc = 512;
    const int cand[6] = {16384, 8192, 4096, 2048, 1024, 512};
    for (int ci = 0; ci < 6; ci++) {
        if ((size_t)16384 * cand[ci] + 8192 <= remain) { Bc = cand[ci]; break; }
    }
    unsigned short* tokc = (unsigned short*)alloc((size_t)2 * Bc * D_DIM * 2);
    unsigned short* qkvc = (unsigned short*)alloc((size_t)2 * Bc * 3 * D_DIM * 2);

    // ---- sort ----
    k_hist<<<NCHUNK, CHUNK, 0, stream>>>(labels, hist);
    k_scan<<<1, NGRP, 0, stream>>>(hist, gstart, counts, scal);
    k_scatter<<<NCHUNK, CHUNK, 0, stream>>>(labels, hist, perm, lss);
    // ---- weight prep ----
    k_cast4<<<(3 * D_DIM * D_DIM / 4 + 255) / 256, 256, 0, stream>>>(intra_in_w, W1b,
                                                                     3 * D_DIM * D_DIM / 4);
    k_cast4<<<(D_DIM * D_DIM / 4 + 255) / 256, 256, 0, stream>>>(lin_w, linwb,
                                                                 D_DIM * D_DIM / 4);
    k_tcast<<<dim3(32, 32), 256, 0, stream>>>(intra_out_w, WoT);
    gemm_bt<1><<<dim3(8, 8), 256, 0, stream>>>(linwb, WoT, 1024, 1024, 1024, nullptr, Wc,
                                               nullptr, nullptr, nullptr, nullptr);
    k_biasc<<<4, 256, 0, stream>>>(lin_w, lin_b, intra_out_b, biasc);
    // ---- inter path (fp32) ----
    k_u<<<dim3(4, NGRP), 256, 0, stream>>>(x, perm, gstart, counts, inter_in_w, inter_in_b, u);
    k_f<<<dim3(4, NGRP), 256, 0, stream>>>(u, counts, inter_out_w, inter_out_b, fbuf);
    k_imean<<<4, 256, 0, stream>>>(fbuf, scal, imean);
    // ---- chunked conv -> qkv -> attention combine ----
    const int nchunks = B_N / Bc;
    for (int c = 0; c < nchunks; c++) {
        const int c0 = c * Bc;
        k_conv<<<Bc, 256, 0, stream>>>(x, perm, lss, conv_w2, conv_b2, conv_w4, conv_b4,
                                       tokc, c0, Bc);
        gemm_bt<0><<<dim3(24, 2 * Bc / 128), 256, 0, stream>>>(
            tokc, W1b, 2 * Bc, 3 * D_DIM, D_DIM, intra_in_b, qkvc, nullptr, nullptr,
            nullptr, nullptr);
        k_attn<<<Bc / 4, 256, 0, stream>>>(qkvc, om, c0, Bc);
    }
    // ---- final folded GEMM + scatter ----
    gemm_bt<2><<<dim3(8, 128), 256, 0, stream>>>(om, Wc, B_N, D_DIM, D_DIM, biasc, nullptr,
                                                 out, perm, lss, imean);
}

// Round 4
// 649.219 us; speedup vs baseline: 1.1089x; 1.0291x over previous
//
#include <hip/hip_runtime.h>
#include <hip/hip_bf16.h>

#define B_N 16384
#define D_DIM 1024
#define NGRP 64
#define NCHUNK 64
#define CHUNK 256

typedef __attribute__((ext_vector_type(8))) short short8;
typedef __attribute__((ext_vector_type(8))) unsigned short ushort8;
typedef __attribute__((ext_vector_type(4))) unsigned short ushort4v;
typedef __attribute__((ext_vector_type(4))) float floatx4;

__device__ __forceinline__ float bf2f(unsigned short h) {
    union { unsigned u; float f; } c; c.u = ((unsigned)h) << 16; return c.f;
}
__device__ __forceinline__ unsigned short f2bf(float f) {
    union { float f; unsigned u; } c; c.f = f;
    unsigned r = c.u + 0x7FFFu + ((c.u >> 16) & 1u);
    return (unsigned short)(r >> 16);
}

__device__ __forceinline__ void gload_lds16(const void* g, void* l) {
    __builtin_amdgcn_global_load_lds(
        (const __attribute__((address_space(1))) unsigned int*)g,
        (__attribute__((address_space(3))) unsigned int*)l, 16, 0, 0);
}

// ---------- stable counting sort ----------
__global__ __launch_bounds__(256) void k_hist(const int* __restrict__ labels,
                                              int* __restrict__ hist) {
    __shared__ int lh[NGRP];
    int t = threadIdx.x, c = blockIdx.x;
    if (t < NGRP) lh[t] = 0;
    __syncthreads();
    int lab = labels[c * CHUNK + t];
    atomicAdd(&lh[lab], 1);
    __syncthreads();
    if (t < NGRP) hist[c * NGRP + t] = lh[t];
}

__global__ void k_scan(int* __restrict__ hist, int* __restrict__ gstart,
                       int* __restrict__ counts, float* __restrict__ scal) {
    __shared__ int cnt[NGRP];
    __shared__ int st[NGRP + 1];
    int g = threadIdx.x;
    int run = 0;
    for (int c = 0; c < NCHUNK; c++) {
        int v = hist[c * NGRP + g];
        hist[c * NGRP + g] = run;
        run += v;
    }
    cnt[g] = run;
    counts[g] = run;
    __syncthreads();
    if (g == 0) {
        int s = 0, np = 0;
        for (int i = 0; i < NGRP; i++) { st[i] = s; s += cnt[i]; np += (cnt[i] > 0); }
        st[NGRP] = s;
        scal[0] = (np > 1) ? 1.0f / (float)(np - 1) : 0.0f;
    }
    __syncthreads();
    gstart[g] = st[g];
    if (g == 0) gstart[NGRP] = st[NGRP];
    for (int c = 0; c < NCHUNK; c++) hist[c * NGRP + g] += st[g];
}

__global__ __launch_bounds__(256) void k_scatter(const int* __restrict__ labels,
                                                 const int* __restrict__ hist,
                                                 int* __restrict__ perm,
                                                 int* __restrict__ ls) {
    __shared__ int lab[CHUNK];
    int c = blockIdx.x, t = threadIdx.x;
    int i = c * CHUNK + t;
    int L = labels[i];
    lab[t] = L;
    __syncthreads();
    int rank = 0;
    for (int j = 0; j < t; j++) rank += (lab[j] == L);
    int pos = hist[c * NGRP + L] + rank;
    perm[pos] = i;
    ls[pos] = L;
}

// ---------- segment conv -> tok chunk (bf16 [2*Bc][D]) ----------
__global__ __launch_bounds__(256) void k_conv(const float* __restrict__ x,
                                              const int* __restrict__ perm,
                                              const int* __restrict__ ls,
                                              const float* __restrict__ w2, const float* __restrict__ b2,
                                              const float* __restrict__ w4, const float* __restrict__ b4,
                                              unsigned short* __restrict__ tok, int c0, int Bc) {
    const int il = blockIdx.x;
    const int i = c0 + il;
    const int li = ls[i];
    const int p0 = perm[i];
    const int pm1 = (i >= 1 && ls[i - 1] == li) ? perm[i - 1] : -1;
    const int pm2 = (i >= 2 && ls[i - 2] == li) ? perm[i - 2] : -1;
    const int pp1 = (i + 1 < B_N && ls[i + 1] == li) ? perm[i + 1] : -1;
    const int c = threadIdx.x * 4;
    floatx4 z = (floatx4)0.0f;
    floatx4 x0 = *(const floatx4*)(x + (size_t)p0 * D_DIM + c);
    floatx4 xm1 = (pm1 >= 0) ? *(const floatx4*)(x + (size_t)pm1 * D_DIM + c) : z;
    floatx4 xm2 = (pm2 >= 0) ? *(const floatx4*)(x + (size_t)pm2 * D_DIM + c) : z;
    floatx4 xp1 = (pp1 >= 0) ? *(const floatx4*)(x + (size_t)pp1 * D_DIM + c) : z;
    const float w20 = w2[0], w21 = w2[1], cb2 = b2[0];
    const float w40 = w4[0], w41 = w4[1], w42 = w4[2], w43 = w4[3], cb4 = b4[0];
    ushort4v o2, o4;
#pragma unroll
    for (int j = 0; j < 4; j++) {
        float t2 = w20 * xm1[j] + w21 * x0[j] + cb2;
        float t4 = w40 * xm2[j] + w41 * xm1[j] + w42 * x0[j] + w43 * xp1[j] + cb4;
        o2[j] = f2bf(t2);
        o4[j] = f2bf(t4);
    }
    *(ushort4v*)(tok + (size_t)il * D_DIM + c) = o2;
    *(ushort4v*)(tok + (size_t)(Bc + il) * D_DIM + c) = o4;
}

// ---------- fused weight prep: cast W1b, linwb + transpose-cast WoT ----------
__global__ __launch_bounds__(256) void k_prep(const float* __restrict__ intra_in_w,
                                              const float* __restrict__ lin_w,
                                              const float* __restrict__ intra_out_w,
                                              unsigned short* __restrict__ W1b,
                                              unsigned short* __restrict__ linwb,
                                              unsigned short* __restrict__ WoT) {
    __shared__ float tile[32][33];
    const int bx = blockIdx.x;
    if (bx < 4096) {
        int i = bx * 256 + threadIdx.x;  // quad index, 4M elems total
        const float* src;
        unsigned short* dst;
        int j;
        if (i < 786432) { src = intra_in_w; dst = W1b; j = i; }
        else { src = lin_w; dst = linwb; j = i - 786432; }
        floatx4 v = *(const floatx4*)(src + (size_t)j * 4);
        ushort4v o;
#pragma unroll
        for (int q = 0; q < 4; q++) o[q] = f2bf(v[q]);
        *(ushort4v*)(dst + (size_t)j * 4) = o;
    } else {
        const int tb = bx - 4096;  // 0..1023
        const int bX = (tb & 31) * 32, bY = (tb >> 5) * 32;
        const int tx = threadIdx.x & 31, ty = threadIdx.x >> 5;
        for (int r = ty; r < 32; r += 8)
            tile[r][tx] = intra_out_w[(size_t)(bY + r) * D_DIM + bX + tx];
        __syncthreads();
        for (int r = ty; r < 32; r += 8)
            WoT[(size_t)(bX + r) * D_DIM + bY + tx] = f2bf(tile[tx][r]);
    }
}

// ---------- inter path (fp32, tiny); blockIdx.y==NGRP computes biasc ----------
__global__ __launch_bounds__(256) void k_u(const float* __restrict__ x,
                                           const int* __restrict__ perm,
                                           const int* __restrict__ gstart,
                                           const int* __restrict__ counts,
                                           const float* __restrict__ Wfull,
                                           const float* __restrict__ bfull,
                                           float* __restrict__ u,
                                           const float* __restrict__ lin_w,
                                           const float* __restrict__ lin_b,
                                           const float* __restrict__ ob,
                                           float* __restrict__ biasc) {
    const int g = blockIdx.y;
    const int n = blockIdx.x * 256 + threadIdx.x;
    __shared__ __align__(16) float xr[D_DIM];
    const bool isb = (g == NGRP);
    int row = 0;
    if (!isb) {
        const int cnt = counts[g];
        row = (cnt > 0) ? perm[gstart[g]] : 0;
    }
    for (int k = threadIdx.x; k < D_DIM; k += 256)
        xr[k] = isb ? ob[k] : x[(size_t)row * D_DIM + k];
    __syncthreads();
    const float* wrow = isb ? (lin_w + (size_t)n * D_DIM)
                            : (Wfull + (size_t)(2 * D_DIM + n) * D_DIM);
    const floatx4* wr4 = (const floatx4*)wrow;
    const floatx4* xr4 = (const floatx4*)xr;
    float s = isb ? lin_b[n] : bfull[2 * D_DIM + n];
    for (int k4 = 0; k4 < D_DIM / 4; k4++) {
        floatx4 a = xr4[k4], b = wr4[k4];
        s += a[0] * b[0] + a[1] * b[1] + a[2] * b[2] + a[3] * b[3];
    }
    if (isb) biasc[n] = s;
    else u[g * D_DIM + n] = s;
}

__global__ __launch_bounds__(256) void k_f(const float* __restrict__ u,
                                           const int* __restrict__ counts,
                                           const float* __restrict__ W,
                                           const float* __restrict__ b,
                                           float* __restrict__ f) {
    const int g = blockIdx.y;
    const int n = blockIdx.x * 256 + threadIdx.x;
    __shared__ __align__(16) float ur[D_DIM];
    const int cnt = counts[g];
    for (int k = threadIdx.x; k < D_DIM; k += 256) ur[k] = u[g * D_DIM + k];
    __syncthreads();
    const floatx4* wr4 = (const floatx4*)(W + (size_t)n * D_DIM);
    const floatx4* ur4 = (const floatx4*)ur;
    float s = b[n];
    for (int k4 = 0; k4 < D_DIM / 4; k4++) {
        floatx4 a = ur4[k4], w = wr4[k4];
        s += a[0] * w[0] + a[1] * w[1] + a[2] * w[2] + a[3] * w[3];
    }
    f[g * D_DIM + n] = (cnt > 0) ? s : 0.0f;
}

__global__ __launch_bounds__(256) void k_imean(const float* __restrict__ f,
                                               const float* __restrict__ scal,
                                               float* __restrict__ im) {
    int c = blockIdx.x * 256 + threadIdx.x;
    float s = 0.0f;
    for (int g = 0; g < NGRP; g++) s += f[g * D_DIM + c];
    float fl = scal[0];
    for (int g = 0; g < NGRP; g++) im[g * D_DIM + c] = (s - f[g * D_DIM + c]) * fl;
}

// ---------- bf16 MFMA GEMM: C[m][n] = sum_k A[m][k]*W[n][k] (+epilogue) ----------
// XOR-swizzled LDS (conflict-free) + XCD-aware block swizzle (L2 locality).
// MODE 0: outb = bf16(acc + bias[n]), row stride N      (qk projection)
// MODE 1: outb = bf16(acc), row stride N                (Wc = lin_w @ intra_out_w)
// MODE 2: outf[perm[m]][n] = acc + bias[n] + imean[ls[m]][n]   (final, scattered)
// MODE 3: v-GEMM: A selected per head (n0>>9), outb[(rowoff+m)*ldc + n] = bf16(acc+bias[n])
template <int MODE>
__global__ __launch_bounds__(256)
void gemm_bt(const unsigned short* __restrict__ A,
             const unsigned short* __restrict__ W,
             int M, int N, int K,
             const float* __restrict__ bias,
             unsigned short* __restrict__ outb,
             float* __restrict__ outf,
             const int* __restrict__ perm,
             const int* __restrict__ ls,
             const float* __restrict__ imean,
             int mhstride, int ldc, int rowoff) {
    __shared__ __align__(16) unsigned short sA[128 * 64];
    __shared__ __align__(16) unsigned short sB[128 * 64];
    const int t = threadIdx.x;
    const int lane = t & 63, wv = t >> 6;
    // XCD-aware swizzle: each XCD (bid%8) owns a contiguous m-stripe x all n-tiles
    int bx = blockIdx.x, by = blockIdx.y;
    const int nX = gridDim.x, nY = gridDim.y;
    if ((nY & 7) == 0) {
        const int bid = by * nX + bx;
        const int xcd = bid & 7, j = bid >> 3;
        const int stripe = nY >> 3;
        by = xcd * stripe + j / nX;
        bx = j % nX;
    }
    const int m0 = by * 128, n0 = bx * 128;
    if (MODE == 3) A += (size_t)(n0 >> 9) * (size_t)mhstride;
    const int wm = (wv & 1) * 64, wn = (wv >> 1) * 64;
    const int l15 = lane & 15, quad = lane >> 4;
    const int sw = l15 & 7;

    floatx4 acc[4][4];
#pragma unroll
    for (int i = 0; i < 4; i++)
#pragma unroll
        for (int j = 0; j < 4; j++) acc[i][j] = (floatx4)0.0f;

    for (int k0 = 0; k0 < K; k0 += 64) {
#pragma unroll
        for (int r = 0; r < 4; r++) {
            const int chunk = r * 256 + wv * 64;
            const int idx = chunk + lane;
            const int row = idx >> 3;
            const int kb = (idx & 7) ^ (row & 7);
            gload_lds16(A + (size_t)(m0 + row) * K + k0 + kb * 8, &sA[chunk * 8]);
            gload_lds16(W + (size_t)(n0 + row) * K + k0 + kb * 8, &sB[chunk * 8]);
        }
        __syncthreads();
#pragma unroll
        for (int kk = 0; kk < 64; kk += 32) {
            const int kc = kk >> 3;
            short8 av[4], bv[4];
#pragma unroll
            for (int mt = 0; mt < 4; mt++)
                av[mt] = *(const short8*)&sA[(wm + mt * 16 + l15) * 64 +
                                             (((kc + quad) ^ sw) << 3)];
#pragma unroll
            for (int nt = 0; nt < 4; nt++)
                bv[nt] = *(const short8*)&sB[(wn + nt * 16 + l15) * 64 +
                                             (((kc + quad) ^ sw) << 3)];
#pragma unroll
            for (int mt = 0; mt < 4; mt++)
#pragma unroll
                for (int nt = 0; nt < 4; nt++)
                    acc[mt][nt] = __builtin_amdgcn_mfma_f32_16x16x32_bf16(
                        av[mt], bv[nt], acc[mt][nt], 0, 0, 0);
        }
        __syncthreads();
    }

    if (MODE != 2) {
        const int ld = (MODE == 3) ? ldc : N;
        const int rb = (MODE == 3) ? rowoff : 0;
#pragma unroll
        for (int nt = 0; nt < 4; nt++) {
            const int gc = n0 + wn + nt * 16 + l15;
            const float bb = (MODE == 1) ? 0.0f : bias[gc];
#pragma unroll
            for (int mt = 0; mt < 4; mt++) {
                const int gr = m0 + wm + mt * 16 + quad * 4;
#pragma unroll
                for (int r = 0; r < 4; r++)
                    outb[(size_t)(rb + gr + r) * ld + gc] = f2bf(acc[mt][nt][r] + bb);
            }
        }
    } else {
        float bb[4];
        int gc4[4];
#pragma unroll
        for (int nt = 0; nt < 4; nt++) {
            gc4[nt] = n0 + wn + nt * 16 + l15;
            bb[nt] = bias[gc4[nt]];
        }
#pragma unroll
        for (int mt = 0; mt < 4; mt++) {
#pragma unroll
            for (int r = 0; r < 4; r++) {
                const int i = m0 + wm + mt * 16 + quad * 4 + r;
                const int orow = perm[i];
                const int lg = ls[i];
#pragma unroll
                for (int nt = 0; nt < 4; nt++)
                    outf[(size_t)orow * N + gc4[nt]] =
                        acc[mt][nt][r] + bb[nt] + imean[lg * D_DIM + gc4[nt]];
            }
        }
    }
}

// ---------- scores -> per-(row,head) combine weights gamma ----------
// qk chunk rows: [t2 rows: q(1024)|k(1024)] then [t4 rows]. gam = (c_t2_h0, c_t4_h0, c_t2_h1, c_t4_h1)
__global__ __launch_bounds__(256) void k_score(const unsigned short* __restrict__ qk,
                                               floatx4* __restrict__ gam, int Bc) {
    const int t = threadIdx.x;
    const int lane = t & 63, wv = t >> 6;
    const int bl = blockIdx.x * 4 + wv;
    const unsigned short* r2 = qk + (size_t)bl * 2048;
    const unsigned short* r4 = qk + (size_t)(Bc + bl) * 2048;
    float cw[4];
#pragma unroll
    for (int h = 0; h < 2; h++) {
        const int off = h * 512 + lane * 8;
        short8 q2 = *(const short8*)(r2 + off);
        short8 q4 = *(const short8*)(r4 + off);
        short8 k2 = *(const short8*)(r2 + 1024 + off);
        short8 k4 = *(const short8*)(r4 + 1024 + off);
        float s22 = 0, s24 = 0, s42 = 0, s44 = 0;
#pragma unroll
        for (int j = 0; j < 8; j++) {
            float q2f = bf2f((unsigned short)q2[j]), q4f = bf2f((unsigned short)q4[j]);
            float k2f = bf2f((unsigned short)k2[j]), k4f = bf2f((unsigned short)k4[j]);
            s22 += q2f * k2f; s24 += q2f * k4f; s42 += q4f * k2f; s44 += q4f * k4f;
        }
#pragma unroll
        for (int d = 32; d > 0; d >>= 1) {
            s22 += __shfl_xor(s22, d, 64);
            s24 += __shfl_xor(s24, d, 64);
            s42 += __shfl_xor(s42, d, 64);
            s44 += __shfl_xor(s44, d, 64);
        }
        const float sc = 0.044194173824159216f;  // 1/sqrt(512)
        s22 *= sc; s24 *= sc; s42 *= sc; s44 *= sc;
        // query t2 row: softmax over keys (t2, t4)
        float m0 = fmaxf(s22, s24), e22 = __expf(s22 - m0), e24 = __expf(s24 - m0);
        float w24 = e24 / (e22 + e24), w22 = 1.0f - w24;
        // query t4 row
        float m1 = fmaxf(s42, s44), e42 = __expf(s42 - m1), e44 = __expf(s44 - m1);
        float w44 = e44 / (e42 + e44), w42 = 1.0f - w44;
        cw[h * 2 + 0] = 0.5f * (w22 + w42);  // weight on v(t2)
        cw[h * 2 + 1] = 0.5f * (w24 + w44);  // weight on v(t4)
    }
    if (lane == 0) {
        floatx4 g;
        g[0] = cw[0]; g[1] = cw[1]; g[2] = cw[2]; g[3] = cw[3];
        gam[bl] = g;
    }
}

// ---------- z = gamma-combined tokens, per head (bf16 [2*Bc][D], head-major) ----------
__global__ __launch_bounds__(256) void k_zprep(const unsigned short* __restrict__ tok,
                                               const floatx4* __restrict__ gam,
                                               unsigned short* __restrict__ z, int Bc) {
    const int idx = blockIdx.x * 256 + threadIdx.x;  // Bc*128 threads
    const int bl = idx >> 7;
    const int seg = (idx & 127) * 8;
    floatx4 g = gam[bl];
    short8 a = *(const short8*)(tok + (size_t)bl * D_DIM + seg);
    short8 b = *(const short8*)(tok + (size_t)(Bc + bl) * D_DIM + seg);
    ushort8 z1, z2;
#pragma unroll
    for (int j = 0; j < 8; j++) {
        float af = bf2f((unsigned short)a[j]), bf = bf2f((unsigned short)b[j]);
        z1[j] = f2bf(g[0] * af + g[1] * bf);
        z2[j] = f2bf(g[2] * af + g[3] * bf);
    }
    *(ushort8*)(z + (size_t)bl * D_DIM + seg) = z1;
    *(ushort8*)(z + (size_t)(Bc + bl) * D_DIM + seg) = z2;
}

extern "C" void kernel_launch(void* const* d_in, const int* in_sizes, int n_in,
                              void* d_out, int out_size, void* d_ws, size_t ws_size,
                              hipStream_t stream) {
    const float* x = (const float*)d_in[0];
    const int* labels = (const int*)d_in[1];
    const float* conv_w2 = (const float*)d_in[3];
    const float* conv_b2 = (const float*)d_in[4];
    const float* conv_w4 = (const float*)d_in[5];
    const float* conv_b4 = (const float*)d_in[6];
    const float* intra_in_w = (const float*)d_in[7];
    const float* intra_in_b = (const float*)d_in[8];
    const float* intra_out_w = (const float*)d_in[9];
    const float* intra_out_b = (const float*)d_in[10];
    const float* inter_in_w = (const float*)d_in[11];
    const float* inter_in_b = (const float*)d_in[12];
    const float* inter_out_w = (const float*)d_in[13];
    const float* inter_out_b = (const float*)d_in[14];
    const float* lin_w = (const float*)d_in[15];
    const float* lin_b = (const float*)d_in[16];
    float* out = (float*)d_out;

    char* p = (char*)d_ws;
    auto alloc = [&](size_t bytes) -> void* {
        void* r = (void*)p;
        p += (bytes + 255) & ~(size_t)255;
        return r;
    };
    // ---- fixed buffers (~45 MB) ----
    int* perm = (int*)alloc(B_N * 4);
    int* lss = (int*)alloc(B_N * 4);
    int* hist = (int*)alloc(NCHUNK * NGRP * 4);
    int* gstart = (int*)alloc((NGRP + 1) * 4);
    int* counts = (int*)alloc(NGRP * 4);
    float* scal = (float*)alloc(4);
    unsigned short* om = (unsigned short*)alloc((size_t)B_N * D_DIM * 2);        // 32 MB
    unsigned short* W1b = (unsigned short*)alloc((size_t)3 * D_DIM * D_DIM * 2); // 6 MB
    unsigned short* linwb = (unsigned short*)alloc((size_t)D_DIM * D_DIM * 2);
    unsigned short* WoT = (unsigned short*)alloc((size_t)D_DIM * D_DIM * 2);
    unsigned short* Wc = (unsigned short*)alloc((size_t)D_DIM * D_DIM * 2);
    float* u = (float*)alloc((size_t)NGRP * D_DIM * 4);
    float* fbuf = (float*)alloc((size_t)NGRP * D_DIM * 4);
    float* imean = (float*)alloc((size_t)NGRP * D_DIM * 4);
    float* biasc = (float*)alloc(D_DIM * 4);

    // ---- adaptive chunk: tok(4096B) + qk(8192B) + z(4096B) + gam(16B) per row ----
    size_t used = (size_t)(p - (char*)d_ws);
    size_t remain = (ws_size > used) ? (ws_size - used) : 0;
    int Bc = 512;
    const int cand[6] = {16384, 8192, 4096, 2048, 1024, 512};
    for (int ci = 0; ci < 6; ci++) {
        if ((size_t)16400 * cand[ci] + 8192 <= remain) { Bc = cand[ci]; break; }
    }
    unsigned short* tokc = (unsigned short*)alloc((size_t)2 * Bc * D_DIM * 2);
    unsigned short* qkc = (unsigned short*)alloc((size_t)2 * Bc * 2 * D_DIM * 2);
    unsigned short* zc = (unsigned short*)alloc((size_t)2 * Bc * D_DIM * 2);
    floatx4* gam = (floatx4*)alloc((size_t)Bc * 16);

    // ---- sort ----
    k_hist<<<NCHUNK, CHUNK, 0, stream>>>(labels, hist);
    k_scan<<<1, NGRP, 0, stream>>>(hist, gstart, counts, scal);
    k_scatter<<<NCHUNK, CHUNK, 0, stream>>>(labels, hist, perm, lss);
    // ---- weight prep (fused casts + transpose) ----
    k_prep<<<4096 + 1024, 256, 0, stream>>>(intra_in_w, lin_w, intra_out_w, W1b, linwb, WoT);
    gemm_bt<1><<<dim3(8, 8), 256, 0, stream>>>(linwb, WoT, 1024, 1024, 1024, nullptr, Wc,
                                               nullptr, nullptr, nullptr, nullptr, 0, 0, 0);
    // ---- inter path (fp32) + biasc folded in ----
    k_u<<<dim3(4, NGRP + 1), 256, 0, stream>>>(x, perm, gstart, counts, inter_in_w,
                                               inter_in_b, u, lin_w, lin_b, intra_out_b,
                                               biasc);
    k_f<<<dim3(4, NGRP), 256, 0, stream>>>(u, counts, inter_out_w, inter_out_b, fbuf);
    k_imean<<<4, 256, 0, stream>>>(fbuf, scal, imean);
    // ---- chunked: conv -> qk GEMM -> scores -> z -> v GEMM (writes om) ----
    const int nchunks = B_N / Bc;
    for (int c = 0; c < nchunks; c++) {
        const int c0 = c * Bc;
        k_conv<<<Bc, 256, 0, stream>>>(x, perm, lss, conv_w2, conv_b2, conv_w4, conv_b4,
                                       tokc, c0, Bc);
        gemm_bt<0><<<dim3(16, 2 * Bc / 128), 256, 0, stream>>>(
            tokc, W1b, 2 * Bc, 2 * D_DIM, D_DIM, intra_in_b, qkc, nullptr, nullptr,
            nullptr, nullptr, 0, 0, 0);
        k_score<<<Bc / 4, 256, 0, stream>>>(qkc, gam, Bc);
        k_zprep<<<Bc / 2, 256, 0, stream>>>(tokc, gam, zc, Bc);
        gemm_bt<3><<<dim3(8, Bc / 128), 256, 0, stream>>>(
            zc, W1b + (size_t)2 * D_DIM * D_DIM, Bc, D_DIM, D_DIM,
            intra_in_b + 2 * D_DIM, om, nullptr, nullptr, nullptr, nullptr,
            Bc * D_DIM, D_DIM, c0);
    }
    // ---- final folded GEMM + scatter ----
    gemm_bt<2><<<dim3(8, 128), 256, 0, stream>>>(om, Wc, B_N, D_DIM, D_DIM, biasc, nullptr,
                                                 out, perm, lss, imean, 0, 0, 0);
}